// Round 2
// baseline (1508.428 us; speedup 1.0000x reference)
//
#include <hip/hip_runtime.h>
#include <stdint.h>

typedef __bf16 bf16x8 __attribute__((ext_vector_type(8)));
typedef float  floatx4 __attribute__((ext_vector_type(4)));

#define T_LEN 512
#define BT    16      // batch rows per block
#define NTHR  256     // 4 waves -> 1 wave/SIMD -> 512 unified regs/wave (no spill)
#define XS    72      // xb row stride (bf16): 144B, rows stagger 16B mod 128 -> conflict-friendly
#define HBS   136     // h bf16 row stride: 272B
#define HFS   132     // final h1 fp32 row stride

#define MFMA(a,b,c) __builtin_amdgcn_mfma_f32_16x16x32_bf16((a),(b),(c),0,0,0)

__device__ __forceinline__ float sigm(float x) {
    return __builtin_amdgcn_rcpf(1.f + exp2f(-1.4426950408889634f * x));
}
__device__ __forceinline__ float tanh_fast(float x) {
    return 2.f * __builtin_amdgcn_rcpf(1.f + exp2f(-2.8853900817779268f * x)) - 1.f;
}

__device__ __forceinline__ bf16x8 wfrag(const float* W, int ldk, int row, int k0) {
    const float* p = W + (size_t)row * ldk + k0;
    bf16x8 r;
    #pragma unroll
    for (int j = 0; j < 8; ++j) r[j] = (__bf16)p[j];
    return r;
}

// One block owns 16 batch rows for the WHOLE sequence, both layers.
// Layer-lag pipeline: iteration tt computes layer0 step tt and layer1 step tt-1.
// All cross-wave traffic is h (bf16, A-fragment layout) + x via double-buffered LDS
// -> exactly ONE barrier per iteration. Gate math stays in MFMA C-layout registers:
// wave w's gate tiles (r,z,n) at cols c,128+c,256+c all correspond to h-cols c,
// so h_new needs no cross-lane exchange. h fp32 state + biases in registers.
__global__ __launch_bounds__(NTHR, 1) void gru_fused(
    const float* __restrict__ x,
    const float* __restrict__ Wih0, const float* __restrict__ Whh0,
    const float* __restrict__ bih0, const float* __restrict__ bhh0,
    const float* __restrict__ Wih1, const float* __restrict__ Whh1,
    const float* __restrict__ bih1, const float* __restrict__ bhh1,
    const float* __restrict__ Wfc,  const float* __restrict__ bfc,
    float* __restrict__ out)
{
    __shared__ __align__(16) __bf16 xb[2][BT * XS];    //  4608 B
    __shared__ __align__(16) __bf16 h0b[2][BT * HBS];  //  8704 B
    __shared__ __align__(16) __bf16 h1b[2][BT * HBS];  //  8704 B
    __shared__ __align__(16) float  hfin[BT * HFS];    //  8448 B -> 30464 B total

    const int tid  = threadIdx.x;
    const int lane = tid & 63;
    const int ln16 = lane & 15;
    const int quad = lane >> 4;
    const int q8   = quad * 8;
    const int wave = tid >> 6;          // 0..3
    const int wcb  = wave * 32;         // wave's h-column base (owns 2 16-col tiles)
    const int brow = blockIdx.x * BT;

    for (int i = tid; i < BT * HBS; i += NTHR) {
        h0b[0][i] = (__bf16)0.f; h0b[1][i] = (__bf16)0.f;
        h1b[0][i] = (__bf16)0.f; h1b[1][i] = (__bf16)0.f;
    }

    // per-lane biases (gate order r,z,n; rows 0..127 r / 128..255 z / 256..383 n)
    float bR0[2], bZ0[2], bI0[2], bH0[2], bR1[2], bZ1[2], bI1[2], bH1[2];
    #pragma unroll
    for (int t2 = 0; t2 < 2; ++t2) {
        const int c = wcb + t2 * 16 + ln16;
        bR0[t2] = bih0[c]       + bhh0[c];
        bZ0[t2] = bih0[128 + c] + bhh0[128 + c];
        bI0[t2] = bih0[256 + c];
        bH0[t2] = bhh0[256 + c];
        bR1[t2] = bih1[c]       + bhh1[c];
        bZ1[t2] = bih1[128 + c] + bhh1[128 + c];
        bI1[t2] = bih1[256 + c];
        bH1[t2] = bhh1[256 + c];
    }

    // weights as resident MFMA B-fragments: [tile][gate r/z/n][K-chunk]
    bf16x8 wI0[2][3][2], wH0[2][3][4], wI1[2][3][4], wH1[2][3][4];  // 84 frags
    #pragma unroll
    for (int t2 = 0; t2 < 2; ++t2) {
        const int c = wcb + t2 * 16 + ln16;
        #pragma unroll
        for (int g = 0; g < 3; ++g) {
            const int row = g * 128 + c;
            #pragma unroll
            for (int q = 0; q < 2; ++q)
                wI0[t2][g][q] = wfrag(Wih0, 64, row, q * 32 + q8);
            #pragma unroll
            for (int q = 0; q < 4; ++q) {
                wH0[t2][g][q] = wfrag(Whh0, 128, row, q * 32 + q8);
                wI1[t2][g][q] = wfrag(Wih1, 128, row, q * 32 + q8);
                wH1[t2][g][q] = wfrag(Whh1, 128, row, q * 32 + q8);
            }
        }
    }

    // fp32 hidden state in registers (C-layout: rows quad*4+i, col wcb+t2*16+ln16)
    float hf0[2][4] = {{0.f,0.f,0.f,0.f},{0.f,0.f,0.f,0.f}};
    float hf1[2][4] = {{0.f,0.f,0.f,0.f},{0.f,0.f,0.f,0.f}};

    // x staging: 4 floats/thread/step, prefetched one step ahead
    const int xrow = tid >> 4;              // 0..15
    const int xi0  = (tid & 15) * 4;        // 0..60
    const float* xbase = x + (size_t)(brow + xrow) * T_LEN * 64 + xi0;
    float4 vx = *(const float4*)xbase;      // x(0)

    for (int tt = 0; tt <= T_LEN; ++tt) {
        {   // stage x(tt); reads of this parity last happened at tt-2 (barrier-separated)
            __bf16* d = &xb[tt & 1][xrow * XS + xi0];
            d[0] = (__bf16)vx.x; d[1] = (__bf16)vx.y;
            d[2] = (__bf16)vx.z; d[3] = (__bf16)vx.w;
        }
        const int tn = (tt + 1 < T_LEN) ? (tt + 1) : (T_LEN - 1);
        vx = *(const float4*)(xbase + (size_t)tn * 64);
        __syncthreads();   // the ONLY barrier per step

        const int R = tt & 1, Wb = R ^ 1;

        // A fragments (shared by all accumulator tiles)
        bf16x8 ax0 = *(const bf16x8*)&xb[R][ln16 * XS + q8];
        bf16x8 ax1 = *(const bf16x8*)&xb[R][ln16 * XS + 32 + q8];
        bf16x8 a0[4], a1[4];
        #pragma unroll
        for (int q = 0; q < 4; ++q) {
            a0[q] = *(const bf16x8*)&h0b[R][ln16 * HBS + q * 32 + q8];
            a1[q] = *(const bf16x8*)&h1b[R][ln16 * HBS + q * 32 + q8];
        }

        #pragma unroll
        for (int t2 = 0; t2 < 2; ++t2) {
            floatx4 r0 = {bR0[t2], bR0[t2], bR0[t2], bR0[t2]};
            floatx4 z0 = {bZ0[t2], bZ0[t2], bZ0[t2], bZ0[t2]};
            floatx4 i0 = {bI0[t2], bI0[t2], bI0[t2], bI0[t2]};
            floatx4 n0 = {bH0[t2], bH0[t2], bH0[t2], bH0[t2]};
            floatx4 r1 = {bR1[t2], bR1[t2], bR1[t2], bR1[t2]};
            floatx4 z1 = {bZ1[t2], bZ1[t2], bZ1[t2], bZ1[t2]};
            floatx4 i1 = {bI1[t2], bI1[t2], bI1[t2], bI1[t2]};
            floatx4 n1 = {bH1[t2], bH1[t2], bH1[t2], bH1[t2]};

            // layer0 input side (x_t, K=64)
            r0 = MFMA(ax0, wI0[t2][0][0], r0); r0 = MFMA(ax1, wI0[t2][0][1], r0);
            z0 = MFMA(ax0, wI0[t2][1][0], z0); z0 = MFMA(ax1, wI0[t2][1][1], z0);
            i0 = MFMA(ax0, wI0[t2][2][0], i0); i0 = MFMA(ax1, wI0[t2][2][1], i0);
            // h-side: a0 feeds both L0 hidden and L1 input (layer-lag); a1 feeds L1 hidden
            #pragma unroll
            for (int q = 0; q < 4; ++q) {
                r0 = MFMA(a0[q], wH0[t2][0][q], r0);
                z0 = MFMA(a0[q], wH0[t2][1][q], z0);
                n0 = MFMA(a0[q], wH0[t2][2][q], n0);
                r1 = MFMA(a0[q], wI1[t2][0][q], r1);
                z1 = MFMA(a0[q], wI1[t2][1][q], z1);
                i1 = MFMA(a0[q], wI1[t2][2][q], i1);
                r1 = MFMA(a1[q], wH1[t2][0][q], r1);
                z1 = MFMA(a1[q], wH1[t2][1][q], z1);
                n1 = MFMA(a1[q], wH1[t2][2][q], n1);
            }

            const int cc = wcb + t2 * 16 + ln16;
            if (tt < T_LEN) {   // layer0 step tt
                #pragma unroll
                for (int i = 0; i < 4; ++i) {
                    const float rg = sigm(r0[i]);
                    const float zg = sigm(z0[i]);
                    const float ng = tanh_fast(i0[i] + rg * n0[i]);
                    const float h  = ng + zg * (hf0[t2][i] - ng);
                    hf0[t2][i] = h;
                    h0b[Wb][(quad * 4 + i) * HBS + cc] = (__bf16)h;
                }
            }
            if (tt > 0) {       // layer1 step tt-1
                #pragma unroll
                for (int i = 0; i < 4; ++i) {
                    const float rg = sigm(r1[i]);
                    const float zg = sigm(z1[i]);
                    const float ng = tanh_fast(i1[i] + rg * n1[i]);
                    const float h  = ng + zg * (hf1[t2][i] - ng);
                    hf1[t2][i] = h;
                    h1b[Wb][(quad * 4 + i) * HBS + cc] = (__bf16)h;
                }
            }
        }
    }

    // final FC: out[b] = h1(T-1)[b,:] . Wfc + bfc
    #pragma unroll
    for (int t2 = 0; t2 < 2; ++t2)
        #pragma unroll
        for (int i = 0; i < 4; ++i)
            hfin[(quad * 4 + i) * HFS + wcb + t2 * 16 + ln16] = hf1[t2][i];
    __syncthreads();
    {
        const int row = tid >> 4, l = tid & 15;
        float s = 0.f;
        #pragma unroll
        for (int k = 0; k < 8; ++k)
            s += hfin[row * HFS + l + 16 * k] * Wfc[l + 16 * k];
        #pragma unroll
        for (int d = 8; d >= 1; d >>= 1) s += __shfl_down(s, d, 16);
        if (l == 0) out[brow + row] = s + bfc[0];
    }
}

extern "C" void kernel_launch(void* const* d_in, const int* in_sizes, int n_in,
                              void* d_out, int out_size, void* d_ws, size_t ws_size,
                              hipStream_t stream) {
    const float* x    = (const float*)d_in[0];
    const float* Wih0 = (const float*)d_in[1];
    const float* Whh0 = (const float*)d_in[2];
    const float* bih0 = (const float*)d_in[3];
    const float* bhh0 = (const float*)d_in[4];
    const float* Wih1 = (const float*)d_in[5];
    const float* Whh1 = (const float*)d_in[6];
    const float* bih1 = (const float*)d_in[7];
    const float* bhh1 = (const float*)d_in[8];
    const float* Wfc  = (const float*)d_in[9];
    const float* bfc  = (const float*)d_in[10];
    float* out = (float*)d_out;

    hipLaunchKernelGGL(gru_fused, dim3(512 / BT), dim3(NTHR), 0, stream,
                       x, Wih0, Whh0, bih0, bhh0, Wih1, Whh1, bih1, bhh1, Wfc, bfc, out);
}

// Round 3
// 1057.050 us; speedup vs baseline: 1.4270x; 1.4270x over previous
//
#include <hip/hip_runtime.h>
#include <stdint.h>

typedef __bf16 bf16x8 __attribute__((ext_vector_type(8)));
typedef float  floatx4 __attribute__((ext_vector_type(4)));

#define T_LEN 512
#define BT    16      // batch rows per pair
#define NTHR  512     // 8 waves, 2 waves/SIMD -> latency hiding, 256 regs/wave
#define NPAIR 32
#define RING  8       // ring slots (steps) per pair
#define XS    72      // xb row stride (bf16)
#define HBS   136     // h bf16 LDS row stride
#define HFS   132     // final h1 fp32 row stride

#define MFMA(a,b,c) __builtin_amdgcn_mfma_f32_16x16x32_bf16((a),(b),(c),0,0,0)

__device__ __forceinline__ float sigm(float x) {
    return __builtin_amdgcn_rcpf(1.f + exp2f(-1.4426950408889634f * x));
}
__device__ __forceinline__ float tanh_fast(float x) {
    return 2.f * __builtin_amdgcn_rcpf(1.f + exp2f(-2.8853900817779268f * x)) - 1.f;
}
__device__ __forceinline__ float gru_h(float pr, float pz, float pin, float phn, float hp) {
    const float r = sigm(pr), z = sigm(pz);
    const float n = tanh_fast(pin + r * phn);
    return n + z * (hp - n);
}
__device__ __forceinline__ bf16x8 wfrag(const float* W, int ldk, int row, int k0) {
    const float* p = W + (size_t)row * ldk + k0;
    bf16x8 r;
    #pragma unroll
    for (int j = 0; j < 8; ++j) r[j] = (__bf16)p[j];
    return r;
}
// flags live in 0xAA-poisoned workspace: accept only plausible step counts
__device__ __forceinline__ uint32_t sane(uint32_t v) { return v <= 513u ? v : 0u; }

// 64 blocks: bid<32 -> layer0 producer for batch rows [bid*16, +16);
//            bid>=32 -> layer1 consumer + FC for same rows (pair = bid-32).
// Pair (i, i+32): same XCD under round-robin dispatch heuristic (i%8 == (i+32)%8).
// h0 sequence flows producer->consumer via a RING-slot ring buffer in d_ws with
// device-scope release/acquire flags (prod flag pf = steps published, cons flag
// cf = slots consumed; both range-checked against poison).
__global__ __launch_bounds__(NTHR, 2) void gru_pipe(
    const float* __restrict__ x,
    const float* __restrict__ Wih0, const float* __restrict__ Whh0,
    const float* __restrict__ bih0, const float* __restrict__ bhh0,
    const float* __restrict__ Wih1, const float* __restrict__ Whh1,
    const float* __restrict__ bih1, const float* __restrict__ bhh1,
    const float* __restrict__ Wfc,  const float* __restrict__ bfc,
    float* __restrict__ out,
    uint32_t* __restrict__ flags, __bf16* __restrict__ ring)
{
    __shared__ __align__(16) __bf16 xb[2][BT * XS];
    __shared__ __align__(16) __bf16 hb[2][BT * HBS];   // L0: h0 | L1: h1
    __shared__ __align__(16) float  hfin[BT * HFS];

    const int tid  = threadIdx.x;
    const int lane = tid & 63;
    const int ln16 = lane & 15;
    const int quad = lane >> 4;
    const int q8   = quad * 8;
    const int wave = tid >> 6;            // 0..7, owns 16 cols c0=16*wave
    const int c16  = wave * 16 + ln16;
    const int bid  = blockIdx.x;
    const bool isL0 = bid < NPAIR;
    const int pair = isL0 ? bid : bid - NPAIR;
    const int brow = pair * BT;

    uint32_t* pf = flags + pair * 64;          // 256B stride per pair
    uint32_t* cf = pf + 32;                    // 128B from pf
    __bf16* ringp = ring + (size_t)pair * RING * BT * 128;

    for (int i = tid; i < BT * HBS; i += NTHR) {
        hb[0][i] = (__bf16)0.f; hb[1][i] = (__bf16)0.f;
    }

    if (isL0) {
        // ---------------- layer-0 producer ----------------
        bf16x8 wI[3][2], wH[3][4];             // 18 frags = 72 regs
        #pragma unroll
        for (int g = 0; g < 3; ++g) {
            #pragma unroll
            for (int q = 0; q < 2; ++q) wI[g][q] = wfrag(Wih0, 64,  g * 128 + c16, q * 32 + q8);
            #pragma unroll
            for (int q = 0; q < 4; ++q) wH[g][q] = wfrag(Whh0, 128, g * 128 + c16, q * 32 + q8);
        }
        const float bR = bih0[c16] + bhh0[c16];
        const float bZ = bih0[128 + c16] + bhh0[128 + c16];
        const float bI = bih0[256 + c16];
        const float bH = bhh0[256 + c16];
        float hf[4] = {0.f, 0.f, 0.f, 0.f};

        const int xrow = tid >> 5;             // 0..15
        const int xi0  = (tid & 31) * 2;       // 0..62
        const float* xbase = x + (size_t)(brow + xrow) * T_LEN * 64 + xi0;
        float2 vx = *(const float2*)xbase;

        for (int t = 0; t < T_LEN; ++t) {
            xb[t & 1][xrow * XS + xi0]     = (__bf16)vx.x;
            xb[t & 1][xrow * XS + xi0 + 1] = (__bf16)vx.y;
            const int tn = (t + 1 < T_LEN) ? t + 1 : T_LEN - 1;
            vx = *(const float2*)(xbase + (size_t)tn * 64);

            if (tid == 0 && t >= RING) {       // don't overwrite unconsumed slot
                while (sane(__hip_atomic_load(cf, __ATOMIC_RELAXED, __HIP_MEMORY_SCOPE_AGENT))
                       < (uint32_t)(t - RING + 1))
                    __builtin_amdgcn_s_sleep(2);
            }
            __syncthreads();   // drains all waves' step t-1 ring stores (vmcnt)
            if (tid == 0 && t > 0)             // publish steps 0..t-1
                __hip_atomic_store(pf, (uint32_t)t, __ATOMIC_RELEASE, __HIP_MEMORY_SCOPE_AGENT);

            bf16x8 ax0 = *(const bf16x8*)&xb[t & 1][ln16 * XS + q8];
            bf16x8 ax1 = *(const bf16x8*)&xb[t & 1][ln16 * XS + 32 + q8];
            bf16x8 ah[4];
            #pragma unroll
            for (int q = 0; q < 4; ++q)
                ah[q] = *(const bf16x8*)&hb[t & 1][ln16 * HBS + q * 32 + q8];

            floatx4 aR  = {bR, bR, bR, bR};
            floatx4 aZ  = {bZ, bZ, bZ, bZ};
            floatx4 aNi = {bI, bI, bI, bI};
            floatx4 aNh = {bH, bH, bH, bH};
            aR  = MFMA(ax0, wI[0][0], aR);  aR  = MFMA(ax1, wI[0][1], aR);
            aZ  = MFMA(ax0, wI[1][0], aZ);  aZ  = MFMA(ax1, wI[1][1], aZ);
            aNi = MFMA(ax0, wI[2][0], aNi); aNi = MFMA(ax1, wI[2][1], aNi);
            #pragma unroll
            for (int q = 0; q < 4; ++q) {
                aR  = MFMA(ah[q], wH[0][q], aR);
                aZ  = MFMA(ah[q], wH[1][q], aZ);
                aNh = MFMA(ah[q], wH[2][q], aNh);
            }

            __bf16* slot = ringp + (size_t)(t % RING) * BT * 128;
            #pragma unroll
            for (int i = 0; i < 4; ++i) {
                const int row = quad * 4 + i;
                const float h = gru_h(aR[i], aZ[i], aNi[i], aNh[i], hf[i]);
                hf[i] = h;
                const __bf16 hb16 = (__bf16)h;
                hb[(t + 1) & 1][row * HBS + c16] = hb16;  // own next-step A source
                slot[row * 128 + c16] = hb16;             // export to consumer
            }
        }
        __syncthreads();
        if (tid == 0)
            __hip_atomic_store(pf, (uint32_t)T_LEN, __ATOMIC_RELEASE, __HIP_MEMORY_SCOPE_AGENT);
    } else {
        // ---------------- layer-1 consumer + FC ----------------
        bf16x8 wI[3][4], wH[3][4];             // 24 frags = 96 regs
        #pragma unroll
        for (int g = 0; g < 3; ++g)
            #pragma unroll
            for (int q = 0; q < 4; ++q) {
                wI[g][q] = wfrag(Wih1, 128, g * 128 + c16, q * 32 + q8);
                wH[g][q] = wfrag(Whh1, 128, g * 128 + c16, q * 32 + q8);
            }
        const float bR = bih1[c16] + bhh1[c16];
        const float bZ = bih1[128 + c16] + bhh1[128 + c16];
        const float bI = bih1[256 + c16];
        const float bH = bhh1[256 + c16];
        float hf[4] = {0.f, 0.f, 0.f, 0.f};

        uint32_t pfv = 0;   // prefetched producer flag (tid 0 only)
        for (int t = 0; t < T_LEN; ++t) {
            if (tid == 0) {   // steady state: pfv already >= t+1 from last step's prefetch
                while (sane(pfv) < (uint32_t)(t + 1)) {
                    pfv = __hip_atomic_load(pf, __ATOMIC_ACQUIRE, __HIP_MEMORY_SCOPE_AGENT);
                    if (sane(pfv) < (uint32_t)(t + 1)) __builtin_amdgcn_s_sleep(2);
                }
            }
            __syncthreads();  // orders tid0's cache-acquire before all waves' loads;
                              // drains step t-1 ring loads (vmcnt) before cons publish
            if (tid == 0 && t > 0)
                __hip_atomic_store(cf, (uint32_t)t, __ATOMIC_RELAXED, __HIP_MEMORY_SCOPE_AGENT);

            const __bf16* slot = ringp + (size_t)(t % RING) * BT * 128;
            bf16x8 a0[4], a1[4];
            #pragma unroll
            for (int q = 0; q < 4; ++q) {
                a0[q] = *(const bf16x8*)(slot + ln16 * 128 + q * 32 + q8);  // coalesced 16B/lane
                a1[q] = *(const bf16x8*)&hb[t & 1][ln16 * HBS + q * 32 + q8];
            }

            floatx4 aR  = {bR, bR, bR, bR};
            floatx4 aZ  = {bZ, bZ, bZ, bZ};
            floatx4 aNi = {bI, bI, bI, bI};
            floatx4 aNh = {bH, bH, bH, bH};
            #pragma unroll
            for (int q = 0; q < 4; ++q) {
                aR  = MFMA(a0[q], wI[0][q], aR);
                aZ  = MFMA(a0[q], wI[1][q], aZ);
                aNi = MFMA(a0[q], wI[2][q], aNi);
                aR  = MFMA(a1[q], wH[0][q], aR);
                aZ  = MFMA(a1[q], wH[1][q], aZ);
                aNh = MFMA(a1[q], wH[2][q], aNh);
            }

            #pragma unroll
            for (int i = 0; i < 4; ++i) {
                const int row = quad * 4 + i;
                const float h = gru_h(aR[i], aZ[i], aNi[i], aNh[i], hf[i]);
                hf[i] = h;
                hb[(t + 1) & 1][row * HBS + c16] = (__bf16)h;
            }

            if (tid == 0)     // prefetch next step's flag; poll latency hides here
                pfv = __hip_atomic_load(pf, __ATOMIC_ACQUIRE, __HIP_MEMORY_SCOPE_AGENT);
        }

        // FC epilogue: out[b] = h1(T-1)[b,:] . Wfc + bfc
        #pragma unroll
        for (int i = 0; i < 4; ++i)
            hfin[(quad * 4 + i) * HFS + c16] = hf[i];
        __syncthreads();
        {
            const int row = tid >> 5, l = tid & 31;
            float s = 0.f;
            #pragma unroll
            for (int k = 0; k < 4; ++k)
                s += hfin[row * HFS + l + 32 * k] * Wfc[l + 32 * k];
            #pragma unroll
            for (int d = 16; d >= 1; d >>= 1) s += __shfl_down(s, d, 32);
            if (l == 0) out[brow + row] = s + bfc[0];
        }
    }
}

extern "C" void kernel_launch(void* const* d_in, const int* in_sizes, int n_in,
                              void* d_out, int out_size, void* d_ws, size_t ws_size,
                              hipStream_t stream) {
    const float* x    = (const float*)d_in[0];
    const float* Wih0 = (const float*)d_in[1];
    const float* Whh0 = (const float*)d_in[2];
    const float* bih0 = (const float*)d_in[3];
    const float* bhh0 = (const float*)d_in[4];
    const float* Wih1 = (const float*)d_in[5];
    const float* Whh1 = (const float*)d_in[6];
    const float* bih1 = (const float*)d_in[7];
    const float* bhh1 = (const float*)d_in[8];
    const float* Wfc  = (const float*)d_in[9];
    const float* bfc  = (const float*)d_in[10];
    float* out = (float*)d_out;

    uint32_t* flags = (uint32_t*)d_ws;                        // 32 pairs * 256 B
    __bf16*   ring  = (__bf16*)((char*)d_ws + 16384);         // 32 pairs * 32 KB

    hipLaunchKernelGGL(gru_pipe, dim3(2 * NPAIR), dim3(NTHR), 0, stream,
                       x, Wih0, Whh0, bih0, bhh0, Wih1, Whh1, bih1, bhh1, Wfc, bfc,
                       out, flags, ring);
}

// Round 4
// 991.762 us; speedup vs baseline: 1.5210x; 1.0658x over previous
//
#include <hip/hip_runtime.h>
#include <stdint.h>

typedef __bf16 bf16x8 __attribute__((ext_vector_type(8)));
typedef float  floatx4 __attribute__((ext_vector_type(4)));

#define T_LEN 512
#define BT    16      // batch rows per block
#define NTHR  512     // 8 waves, 2 waves/SIMD
#define XS    72      // xb row stride (bf16)
#define HBS   136     // h bf16 LDS row stride
#define HFS   132     // final h1 fp32 row stride

#define MFMA(a,b,c) __builtin_amdgcn_mfma_f32_16x16x32_bf16((a),(b),(c),0,0,0)

__device__ __forceinline__ float sigm(float x) {
    return __builtin_amdgcn_rcpf(1.f + exp2f(-1.4426950408889634f * x));
}
__device__ __forceinline__ float tanh_fast(float x) {
    return 2.f * __builtin_amdgcn_rcpf(1.f + exp2f(-2.8853900817779268f * x)) - 1.f;
}
__device__ __forceinline__ float gru_h(float pr, float pz, float pin, float phn, float hp) {
    const float r = sigm(pr), z = sigm(pz);
    const float n = tanh_fast(pin + r * phn);
    return n + z * (hp - n);
}
__device__ __forceinline__ bf16x8 wfrag(const float* W, int ldk, int row, int k0) {
    const float* p = W + (size_t)row * ldk + k0;
    bf16x8 r;
    #pragma unroll
    for (int j = 0; j < 8; ++j) r[j] = (__bf16)p[j];
    return r;
}

// One block = 16 batch rows, BOTH layers, whole sequence. 8 waves; wave w owns
// gate columns [16w,16w+16) for both layers -> 42 B-fragments = 168 VGPRs/wave,
// fits the 256-reg budget at 2 waves/SIMD (no remat, latency hiding).
// Layer-lag: iteration tt computes L0 step tt and L1 step tt-1 -> ONE barrier/step.
// L1's input A-frags (h0(tt-1)) are the SAME registers as L0's hidden A-frags.
__global__ __launch_bounds__(NTHR, 2) void gru_fused(
    const float* __restrict__ x,
    const float* __restrict__ Wih0, const float* __restrict__ Whh0,
    const float* __restrict__ bih0, const float* __restrict__ bhh0,
    const float* __restrict__ Wih1, const float* __restrict__ Whh1,
    const float* __restrict__ bih1, const float* __restrict__ bhh1,
    const float* __restrict__ Wfc,  const float* __restrict__ bfc,
    float* __restrict__ out)
{
    __shared__ __align__(16) __bf16 xb[2][BT * XS];    //  4608 B
    __shared__ __align__(16) __bf16 h0b[2][BT * HBS];  //  8704 B
    __shared__ __align__(16) __bf16 h1b[2][BT * HBS];  //  8704 B
    __shared__ __align__(16) float  hfin[BT * HFS];    //  8448 B -> 30464 B

    const int tid  = threadIdx.x;
    const int lane = tid & 63;
    const int ln16 = lane & 15;
    const int quad = lane >> 4;
    const int q8   = quad * 8;
    const int wave = tid >> 6;            // 0..7
    const int c16  = wave * 16 + ln16;    // wave's gate/h column
    const int brow = blockIdx.x * BT;

    for (int i = tid; i < BT * HBS; i += NTHR) {
        h0b[0][i] = (__bf16)0.f; h0b[1][i] = (__bf16)0.f;
        h1b[0][i] = (__bf16)0.f; h1b[1][i] = (__bf16)0.f;
    }

    // biases (gate order r,z,n; n keeps i/h sides separate)
    const float bR0 = bih0[c16] + bhh0[c16];
    const float bZ0 = bih0[128 + c16] + bhh0[128 + c16];
    const float bI0 = bih0[256 + c16];
    const float bH0 = bhh0[256 + c16];
    const float bR1 = bih1[c16] + bhh1[c16];
    const float bZ1 = bih1[128 + c16] + bhh1[128 + c16];
    const float bI1 = bih1[256 + c16];
    const float bH1 = bhh1[256 + c16];

    // resident weight B-fragments: 6+12+12+12 = 42 frags = 168 VGPRs
    bf16x8 wI0[3][2], wH0[3][4], wI1[3][4], wH1[3][4];
    #pragma unroll
    for (int g = 0; g < 3; ++g) {
        const int row = g * 128 + c16;
        #pragma unroll
        for (int q = 0; q < 2; ++q) wI0[g][q] = wfrag(Wih0, 64, row, q * 32 + q8);
        #pragma unroll
        for (int q = 0; q < 4; ++q) {
            wH0[g][q] = wfrag(Whh0, 128, row, q * 32 + q8);
            wI1[g][q] = wfrag(Wih1, 128, row, q * 32 + q8);
            wH1[g][q] = wfrag(Whh1, 128, row, q * 32 + q8);
        }
    }

    // fp32 hidden state in C-layout registers (row quad*4+i, col c16)
    float hf0[4] = {0.f, 0.f, 0.f, 0.f};
    float hf1[4] = {0.f, 0.f, 0.f, 0.f};

    // x staging: 2 floats/thread/step, prefetched one step ahead
    const int xrow = tid >> 5;            // 0..15
    const int xi0  = (tid & 31) * 2;      // 0..62
    const float* xbase = x + (size_t)(brow + xrow) * T_LEN * 64 + xi0;
    float2 vx = *(const float2*)xbase;    // x(0)

    for (int tt = 0; tt <= T_LEN; ++tt) {
        xb[tt & 1][xrow * XS + xi0]     = (__bf16)vx.x;
        xb[tt & 1][xrow * XS + xi0 + 1] = (__bf16)vx.y;
        const int tn = (tt + 1 < T_LEN) ? tt + 1 : T_LEN - 1;
        vx = *(const float2*)(xbase + (size_t)tn * 64);
        __syncthreads();                  // the ONLY barrier per step

        const int R = tt & 1, Wn = R ^ 1;

        // h0(tt-1) A-frags: feed L0 hidden side AND L1 input side
        bf16x8 ah[4];
        #pragma unroll
        for (int q = 0; q < 4; ++q)
            ah[q] = *(const bf16x8*)&h0b[R][ln16 * HBS + q * 32 + q8];

        if (tt < T_LEN) {                 // ---- layer0 step tt ----
            bf16x8 ax0 = *(const bf16x8*)&xb[R][ln16 * XS + q8];
            bf16x8 ax1 = *(const bf16x8*)&xb[R][ln16 * XS + 32 + q8];
            floatx4 aR  = {bR0, bR0, bR0, bR0};
            floatx4 aZ  = {bZ0, bZ0, bZ0, bZ0};
            floatx4 aNi = {bI0, bI0, bI0, bI0};
            floatx4 aNh = {bH0, bH0, bH0, bH0};
            aR  = MFMA(ax0, wI0[0][0], aR);  aR  = MFMA(ax1, wI0[0][1], aR);
            aZ  = MFMA(ax0, wI0[1][0], aZ);  aZ  = MFMA(ax1, wI0[1][1], aZ);
            aNi = MFMA(ax0, wI0[2][0], aNi); aNi = MFMA(ax1, wI0[2][1], aNi);
            #pragma unroll
            for (int q = 0; q < 4; ++q) {
                aR  = MFMA(ah[q], wH0[0][q], aR);
                aZ  = MFMA(ah[q], wH0[1][q], aZ);
                aNh = MFMA(ah[q], wH0[2][q], aNh);
            }
            #pragma unroll
            for (int i = 0; i < 4; ++i) {
                const float h = gru_h(aR[i], aZ[i], aNi[i], aNh[i], hf0[i]);
                hf0[i] = h;
                h0b[Wn][(quad * 4 + i) * HBS + c16] = (__bf16)h;
            }
        }

        if (tt > 0) {                     // ---- layer1 step tt-1 ----
            floatx4 aR  = {bR1, bR1, bR1, bR1};
            floatx4 aZ  = {bZ1, bZ1, bZ1, bZ1};
            floatx4 aNi = {bI1, bI1, bI1, bI1};
            floatx4 aNh = {bH1, bH1, bH1, bH1};
            #pragma unroll
            for (int q = 0; q < 4; ++q) {   // input side from ah (shared regs)
                aR  = MFMA(ah[q], wI1[0][q], aR);
                aZ  = MFMA(ah[q], wI1[1][q], aZ);
                aNi = MFMA(ah[q], wI1[2][q], aNi);
            }
            #pragma unroll
            for (int q = 0; q < 4; ++q) {   // hidden side, loaded per-q (pressure)
                bf16x8 a1 = *(const bf16x8*)&h1b[R][ln16 * HBS + q * 32 + q8];
                aR  = MFMA(a1, wH1[0][q], aR);
                aZ  = MFMA(a1, wH1[1][q], aZ);
                aNh = MFMA(a1, wH1[2][q], aNh);
            }
            #pragma unroll
            for (int i = 0; i < 4; ++i) {
                const float h = gru_h(aR[i], aZ[i], aNi[i], aNh[i], hf1[i]);
                hf1[i] = h;
                h1b[Wn][(quad * 4 + i) * HBS + c16] = (__bf16)h;
            }
        }
    }

    // final FC: out[b] = h1(T-1)[b,:] . Wfc + bfc
    #pragma unroll
    for (int i = 0; i < 4; ++i)
        hfin[(quad * 4 + i) * HFS + c16] = hf1[i];
    __syncthreads();
    {
        const int row = tid >> 5, l = tid & 31;
        float s = 0.f;
        #pragma unroll
        for (int k = 0; k < 4; ++k)
            s += hfin[row * HFS + l + 32 * k] * Wfc[l + 32 * k];
        #pragma unroll
        for (int d = 16; d >= 1; d >>= 1) s += __shfl_down(s, d, 32);
        if (l == 0) out[brow + row] = s + bfc[0];
    }
}

extern "C" void kernel_launch(void* const* d_in, const int* in_sizes, int n_in,
                              void* d_out, int out_size, void* d_ws, size_t ws_size,
                              hipStream_t stream) {
    const float* x    = (const float*)d_in[0];
    const float* Wih0 = (const float*)d_in[1];
    const float* Whh0 = (const float*)d_in[2];
    const float* bih0 = (const float*)d_in[3];
    const float* bhh0 = (const float*)d_in[4];
    const float* Wih1 = (const float*)d_in[5];
    const float* Whh1 = (const float*)d_in[6];
    const float* bih1 = (const float*)d_in[7];
    const float* bhh1 = (const float*)d_in[8];
    const float* Wfc  = (const float*)d_in[9];
    const float* bfc  = (const float*)d_in[10];
    float* out = (float*)d_out;

    hipLaunchKernelGGL(gru_fused, dim3(512 / BT), dim3(NTHR), 0, stream,
                       x, Wih0, Whh0, bih0, bhh0, Wih1, Whh1, bih1, bhh1, Wfc, bfc, out);
}

// Round 5
// 990.098 us; speedup vs baseline: 1.5235x; 1.0017x over previous
//
#include <hip/hip_runtime.h>
#include <stdint.h>

typedef __bf16 bf16x8 __attribute__((ext_vector_type(8)));
typedef float  floatx4 __attribute__((ext_vector_type(4)));

#define T_LEN 512
#define BT    16      // batch rows per block
#define NTHR  512     // 8 waves, 2 waves/SIMD
#define XS    72      // xb row stride (bf16)
#define HBS   136     // h bf16 LDS row stride
#define HFS   132     // final h1 fp32 row stride

// bf16 weight image offsets in d_ws (elements)
#define W0I_OFF 0
#define W0H_OFF 24576
#define W1I_OFF 73728
#define W1H_OFF 122880
#define W_TOTAL 172032

#define MFMA(a,b,c) __builtin_amdgcn_mfma_f32_16x16x32_bf16((a),(b),(c),0,0,0)

__device__ __forceinline__ float sigm(float x) {
    return __builtin_amdgcn_rcpf(1.f + exp2f(-1.4426950408889634f * x));
}
__device__ __forceinline__ float tanh_fast(float x) {
    return 2.f * __builtin_amdgcn_rcpf(1.f + exp2f(-2.8853900817779268f * x)) - 1.f;
}
__device__ __forceinline__ float gru_h(float pr, float pz, float pin, float phn, float hp) {
    const float r = sigm(pr), z = sigm(pz);
    const float n = tanh_fast(pin + r * phn);
    return n + z * (hp - n);
}
// single aligned 16B load -- no conversion chain, cheap even if re-issued per step
__device__ __forceinline__ bf16x8 wfrag16(const __bf16* W, int ldk, int row, int k0) {
    return *(const bf16x8*)(W + (size_t)row * ldk + k0);
}

// prologue: fp32 weights -> bf16 image in workspace (row-major, same shapes)
__global__ void convert_weights(const float* __restrict__ Wih0, const float* __restrict__ Whh0,
                                const float* __restrict__ Wih1, const float* __restrict__ Whh1,
                                __bf16* __restrict__ dst) {
    const int i = blockIdx.x * 256 + threadIdx.x;
    if (i >= W_TOTAL) return;
    float v;
    if (i < W0H_OFF)      v = Wih0[i];
    else if (i < W1I_OFF) v = Whh0[i - W0H_OFF];
    else if (i < W1H_OFF) v = Wih1[i - W1I_OFF];
    else                  v = Whh1[i - W1H_OFF];
    dst[i] = (__bf16)v;
}

// One block = 16 batch rows, BOTH layers, whole sequence. 8 waves; wave w owns
// gate columns [16w,16w+16) for both layers. Weight B-fragments come from the
// bf16 image: 42 frags = 168 regs if resident; if the allocator reloads some,
// each reload is one L2-hit dwordx4 (latency-hidden), not an 8-cvt VALU chain.
// Layer-lag: iteration tt computes L0 step tt and L1 step tt-1 -> ONE barrier/step.
__global__ __launch_bounds__(NTHR, 2) void gru_fused(
    const float* __restrict__ x,
    const __bf16* __restrict__ wimg,
    const float* __restrict__ bih0, const float* __restrict__ bhh0,
    const float* __restrict__ bih1, const float* __restrict__ bhh1,
    const float* __restrict__ Wfc,  const float* __restrict__ bfc,
    float* __restrict__ out)
{
    __shared__ __align__(16) __bf16 xb[2][BT * XS];    //  4608 B
    __shared__ __align__(16) __bf16 h0b[2][BT * HBS];  //  8704 B
    __shared__ __align__(16) __bf16 h1b[2][BT * HBS];  //  8704 B
    __shared__ __align__(16) float  hfin[BT * HFS];    //  8448 B -> 30464 B

    const int tid  = threadIdx.x;
    const int lane = tid & 63;
    const int ln16 = lane & 15;
    const int quad = lane >> 4;
    const int q8   = quad * 8;
    const int wave = tid >> 6;            // 0..7
    const int c16  = wave * 16 + ln16;    // wave's gate/h column
    const int brow = blockIdx.x * BT;

    const __bf16* W0i = wimg + W0I_OFF;
    const __bf16* W0h = wimg + W0H_OFF;
    const __bf16* W1i = wimg + W1I_OFF;
    const __bf16* W1h = wimg + W1H_OFF;

    for (int i = tid; i < BT * HBS; i += NTHR) {
        h0b[0][i] = (__bf16)0.f; h0b[1][i] = (__bf16)0.f;
        h1b[0][i] = (__bf16)0.f; h1b[1][i] = (__bf16)0.f;
    }

    // biases (gate order r,z,n; n keeps i/h sides separate)
    const float bR0 = bih0[c16] + bhh0[c16];
    const float bZ0 = bih0[128 + c16] + bhh0[128 + c16];
    const float bI0 = bih0[256 + c16];
    const float bH0 = bhh0[256 + c16];
    const float bR1 = bih1[c16] + bhh1[c16];
    const float bZ1 = bih1[128 + c16] + bhh1[128 + c16];
    const float bI1 = bih1[256 + c16];
    const float bH1 = bhh1[256 + c16];

    // resident weight B-fragments: 6+12+12+12 = 42 frags = 168 VGPRs
    bf16x8 wI0[3][2], wH0[3][4], wI1[3][4], wH1[3][4];
    #pragma unroll
    for (int g = 0; g < 3; ++g) {
        const int row = g * 128 + c16;
        #pragma unroll
        for (int q = 0; q < 2; ++q) wI0[g][q] = wfrag16(W0i, 64, row, q * 32 + q8);
        #pragma unroll
        for (int q = 0; q < 4; ++q) {
            wH0[g][q] = wfrag16(W0h, 128, row, q * 32 + q8);
            wI1[g][q] = wfrag16(W1i, 128, row, q * 32 + q8);
            wH1[g][q] = wfrag16(W1h, 128, row, q * 32 + q8);
        }
    }

    // fp32 hidden state in C-layout registers (row quad*4+i, col c16)
    float hf0[4] = {0.f, 0.f, 0.f, 0.f};
    float hf1[4] = {0.f, 0.f, 0.f, 0.f};

    // x staging: 2 floats/thread/step, prefetched one step ahead
    const int xrow = tid >> 5;            // 0..15
    const int xi0  = (tid & 31) * 2;      // 0..62
    const float* xbase = x + (size_t)(brow + xrow) * T_LEN * 64 + xi0;
    float2 vx = *(const float2*)xbase;    // x(0)

    for (int tt = 0; tt <= T_LEN; ++tt) {
        xb[tt & 1][xrow * XS + xi0]     = (__bf16)vx.x;
        xb[tt & 1][xrow * XS + xi0 + 1] = (__bf16)vx.y;
        const int tn = (tt + 1 < T_LEN) ? tt + 1 : T_LEN - 1;
        vx = *(const float2*)(xbase + (size_t)tn * 64);
        __syncthreads();                  // the ONLY barrier per step

        const int R = tt & 1, Wn = R ^ 1;

        // h0(tt-1) A-frags: feed L0 hidden side AND L1 input side
        bf16x8 ah[4];
        #pragma unroll
        for (int q = 0; q < 4; ++q)
            ah[q] = *(const bf16x8*)&h0b[R][ln16 * HBS + q * 32 + q8];

        if (tt < T_LEN) {                 // ---- layer0 step tt ----
            bf16x8 ax0 = *(const bf16x8*)&xb[R][ln16 * XS + q8];
            bf16x8 ax1 = *(const bf16x8*)&xb[R][ln16 * XS + 32 + q8];
            floatx4 aR  = {bR0, bR0, bR0, bR0};
            floatx4 aZ  = {bZ0, bZ0, bZ0, bZ0};
            floatx4 aNi = {bI0, bI0, bI0, bI0};
            floatx4 aNh = {bH0, bH0, bH0, bH0};
            aR  = MFMA(ax0, wI0[0][0], aR);  aR  = MFMA(ax1, wI0[0][1], aR);
            aZ  = MFMA(ax0, wI0[1][0], aZ);  aZ  = MFMA(ax1, wI0[1][1], aZ);
            aNi = MFMA(ax0, wI0[2][0], aNi); aNi = MFMA(ax1, wI0[2][1], aNi);
            #pragma unroll
            for (int q = 0; q < 4; ++q) {
                aR  = MFMA(ah[q], wH0[0][q], aR);
                aZ  = MFMA(ah[q], wH0[1][q], aZ);
                aNh = MFMA(ah[q], wH0[2][q], aNh);
            }
            #pragma unroll
            for (int i = 0; i < 4; ++i) {
                const float h = gru_h(aR[i], aZ[i], aNi[i], aNh[i], hf0[i]);
                hf0[i] = h;
                h0b[Wn][(quad * 4 + i) * HBS + c16] = (__bf16)h;
            }
        }

        if (tt > 0) {                     // ---- layer1 step tt-1 ----
            floatx4 aR  = {bR1, bR1, bR1, bR1};
            floatx4 aZ  = {bZ1, bZ1, bZ1, bZ1};
            floatx4 aNi = {bI1, bI1, bI1, bI1};
            floatx4 aNh = {bH1, bH1, bH1, bH1};
            #pragma unroll
            for (int q = 0; q < 4; ++q) {   // input side from ah (shared regs)
                aR  = MFMA(ah[q], wI1[0][q], aR);
                aZ  = MFMA(ah[q], wI1[1][q], aZ);
                aNi = MFMA(ah[q], wI1[2][q], aNi);
            }
            #pragma unroll
            for (int q = 0; q < 4; ++q) {   // hidden side
                bf16x8 a1 = *(const bf16x8*)&h1b[R][ln16 * HBS + q * 32 + q8];
                aR  = MFMA(a1, wH1[0][q], aR);
                aZ  = MFMA(a1, wH1[1][q], aZ);
                aNh = MFMA(a1, wH1[2][q], aNh);
            }
            #pragma unroll
            for (int i = 0; i < 4; ++i) {
                const float h = gru_h(aR[i], aZ[i], aNi[i], aNh[i], hf1[i]);
                hf1[i] = h;
                h1b[Wn][(quad * 4 + i) * HBS + c16] = (__bf16)h;
            }
        }
    }

    // final FC: out[b] = h1(T-1)[b,:] . Wfc + bfc
    #pragma unroll
    for (int i = 0; i < 4; ++i)
        hfin[(quad * 4 + i) * HFS + c16] = hf1[i];
    __syncthreads();
    {
        const int row = tid >> 5, l = tid & 31;
        float s = 0.f;
        #pragma unroll
        for (int k = 0; k < 4; ++k)
            s += hfin[row * HFS + l + 32 * k] * Wfc[l + 32 * k];
        #pragma unroll
        for (int d = 16; d >= 1; d >>= 1) s += __shfl_down(s, d, 32);
        if (l == 0) out[brow + row] = s + bfc[0];
    }
}

extern "C" void kernel_launch(void* const* d_in, const int* in_sizes, int n_in,
                              void* d_out, int out_size, void* d_ws, size_t ws_size,
                              hipStream_t stream) {
    const float* x    = (const float*)d_in[0];
    const float* Wih0 = (const float*)d_in[1];
    const float* Whh0 = (const float*)d_in[2];
    const float* bih0 = (const float*)d_in[3];
    const float* bhh0 = (const float*)d_in[4];
    const float* Wih1 = (const float*)d_in[5];
    const float* Whh1 = (const float*)d_in[6];
    const float* bih1 = (const float*)d_in[7];
    const float* bhh1 = (const float*)d_in[8];
    const float* Wfc  = (const float*)d_in[9];
    const float* bfc  = (const float*)d_in[10];
    float* out = (float*)d_out;

    __bf16* wimg = (__bf16*)d_ws;   // 344 KB bf16 weight image

    hipLaunchKernelGGL(convert_weights, dim3((W_TOTAL + 255) / 256), dim3(256), 0, stream,
                       Wih0, Whh0, Wih1, Whh1, wimg);
    hipLaunchKernelGGL(gru_fused, dim3(512 / BT), dim3(NTHR), 0, stream,
                       x, wimg, bih0, bhh0, bih1, bhh1, Wfc, bfc, out);
}